// Round 7
// baseline (9326.197 us; speedup 1.0000x reference)
//
#include <hip/hip_runtime.h>
#include <hip/hip_bf16.h>

#define S_LEN   512
#define BATCH   64
#define DH      512
#define KDIM    1024      // 2*DH (concat [h, x])
#define NCOLS   64        // 4 gates * 16 hidden units per WG
#define WGL     32        // WGs per layer
#define NWG     64
#define THREADS 256
#define LDS_BYTES (NCOLS * KDIM * 2)   // 131072 B weights per WG

typedef __attribute__((ext_vector_type(8))) unsigned short u16x8;
typedef __attribute__((ext_vector_type(8))) __bf16         bf16x8;
typedef __attribute__((ext_vector_type(4))) float          f32x4;
typedef __attribute__((ext_vector_type(4))) unsigned       u32x4;

__device__ __forceinline__ unsigned short f2bf(float f) {
    unsigned u = __float_as_uint(f);
    return (unsigned short)((u + 0x7fffu + ((u >> 16) & 1u)) >> 16);   // RNE
}
__device__ __forceinline__ float sigmoid_f(float x) { return 1.f / (1.f + __expf(-x)); }
__device__ __forceinline__ float tanh_f(float x) {
    float e = __expf(2.f * x);
    return 1.f - 2.f / (e + 1.f);
}
__device__ __forceinline__ f32x4 mfma16(bf16x8 a, bf16x8 b, f32x4 c) {
    return __builtin_amdgcn_mfma_f32_16x16x32_bf16(a, b, c, 0, 0, 0);
}
// 32-bit agent-scope relaxed atomics: the exact instruction class r5's barrier
// proved working (lower to global_load/store_dword sc0 sc1, compiler-tracked).
__device__ __forceinline__ unsigned ld_coh32(const unsigned* p) {
    return __hip_atomic_load(p, __ATOMIC_RELAXED, __HIP_MEMORY_SCOPE_AGENT);
}
__device__ __forceinline__ void st_coh32(unsigned* p, unsigned v) {
    __hip_atomic_store(p, v, __ATOMIC_RELAXED, __HIP_MEMORY_SCOPE_AGENT);
}

// ws layout:
//   ushort[0]      : h0buf [2][64][512]  bf16    layer0 h ping-pong
//   ushort[65536]  : hx1buf[2][64][1024] bf16    layer1 [h,x] ping-pong
//   byte 393216    : flags[64] uint              per-WG monotonic barrier flags
#define WS_H0    0
#define WS_HX1   (2 * BATCH * DH)
#define WS_BAR_B 393216

__global__ void lstm_init(const float* __restrict__ seq,
                          const float* __restrict__ h_init,
                          unsigned short* __restrict__ ws) {
    int i = blockIdx.x * blockDim.x + threadIdx.x;   // 0 .. 32767
    unsigned* flags = (unsigned*)((char*)ws + WS_BAR_B);
    if (i < NWG) flags[i] = 0;                       // re-zeroed every launch
    if (i < BATCH * DH) {
        int row = i >> 9;
        int col = i & 511;
        ws[WS_H0 + row * DH + col] = f2bf(h_init[i]);                    // h0 par0
        ws[WS_HX1 + BATCH * KDIM + row * KDIM + col] =                   // hx1 par1 h-part
            f2bf(h_init[(size_t)BATCH * DH + i]);
    }
}

__global__ __launch_bounds__(THREADS, 1)
void lstm_main(const float* __restrict__ seq,
               const float* __restrict__ Wf, const float* __restrict__ Bf,
               const float* __restrict__ Wi, const float* __restrict__ Bi,
               const float* __restrict__ Wc, const float* __restrict__ Bc,
               const float* __restrict__ Wo, const float* __restrict__ Bo,
               float* __restrict__ out, unsigned short* __restrict__ ws)
{
    extern __shared__ unsigned short wlds[];   // [NCOLS][KDIM] bf16, XOR-swizzled

    const int wg    = blockIdx.x;
    const int layer = (wg >= WGL) ? 1 : 0;
    const int wid   = layer ? wg - WGL : wg;
    const int jbase = wid * 16;
    const int tid   = threadIdx.x;
    const int lane  = tid & 63;
    const int wave  = tid >> 6;

    unsigned short* h0b  = ws + WS_H0;
    unsigned short* hx1b = ws + WS_HX1;
    unsigned* flags = (unsigned*)((char*)ws + WS_BAR_B);

    // ---- stage this WG's weight slice into LDS (bf16, swizzled), once ----
    {
        const size_t woff = (size_t)layer * KDIM * DH;
        const float* Wg[4] = { Wf + woff, Wi + woff, Wc + woff, Wo + woff };
        for (int idx = tid; idx < NCOLS * KDIM; idx += THREADS) {
            int mcol = idx & (NCOLS - 1);          // gate*16 + unit
            int k    = idx >> 6;
            float w  = Wg[mcol >> 4][(size_t)k * DH + jbase + (mcol & 15)];
            unsigned byte = ((unsigned)mcol * 2048u + (unsigned)k * 2u)
                          ^ (((unsigned)mcol & 7u) << 4);
            wlds[byte >> 1] = f2bf(w);
        }
    }

    // ---- transposed-MFMA geometry: A=weights (rows=16 units), B=acts (cols=16 batch)
    // D mapping (m89): col = lane&15 -> batch, row = (lane>>4)*4 + r -> unit.
    const int ln  = lane & 15;
    const int lq  = lane >> 4;
    const int b   = wave * 16 + ln;          // this lane's batch row
    const int jq  = jbase + (lq << 2);       // first of 4 consecutive unit cols
    const int klo = lq * 8;                  // k offset within each K=32 chunk
    const unsigned sw  = ((unsigned)(lane & 7)) << 4;
    const unsigned wbF = (0u * 16 + (unsigned)ln) * 2048u;
    const unsigned wbI = (1u * 16 + (unsigned)ln) * 2048u;
    const unsigned wbC = (2u * 16 + (unsigned)ln) * 2048u;
    const unsigned wbO = (3u * 16 + (unsigned)ln) * 2048u;

    float bFa[4], bIa[4], bCa[4], bOa[4];
    #pragma unroll
    for (int r = 0; r < 4; ++r) {
        bFa[r] = Bf[layer * DH + jq + r];
        bIa[r] = Bi[layer * DH + jq + r];
        bCa[r] = Bc[layer * DH + jq + r];
        bOa[r] = Bo[layer * DH + jq + r];
    }
    __syncthreads();

    float cs[4] = {0.f, 0.f, 0.f, 0.f};

    for (int it = 0; it <= S_LEN; ++it) {
        const bool active = layer ? (it >= 1) : (it < S_LEN);
        const int  t      = layer ? it - 1 : it;

        if (active) {
            const int par = it & 1;
            f32x4 eF = {0,0,0,0}, eI = {0,0,0,0}, eC = {0,0,0,0}, eO = {0,0,0,0};
            f32x4 oF = {0,0,0,0}, oI = {0,0,0,0}, oC = {0,0,0,0}, oO = {0,0,0,0};

            #define CONS(s_, av_) do {                                                 \
                const unsigned kb = ((unsigned)(s_) * 64u + (unsigned)klo * 2u) ^ sw;  \
                bf16x8 wF = __builtin_bit_cast(bf16x8, *(const u16x8*)((const char*)wlds + wbF + kb)); \
                bf16x8 wI = __builtin_bit_cast(bf16x8, *(const u16x8*)((const char*)wlds + wbI + kb)); \
                bf16x8 wC = __builtin_bit_cast(bf16x8, *(const u16x8*)((const char*)wlds + wbC + kb)); \
                bf16x8 wO = __builtin_bit_cast(bf16x8, *(const u16x8*)((const char*)wlds + wbO + kb)); \
                if ((s_) & 1) {                                                        \
                    oF = mfma16(wF, (av_), oF); oI = mfma16(wI, (av_), oI);            \
                    oC = mfma16(wC, (av_), oC); oO = mfma16(wO, (av_), oO);            \
                } else {                                                               \
                    eF = mfma16(wF, (av_), eF); eI = mfma16(wI, (av_), eI);            \
                    eC = mfma16(wC, (av_), eC); eO = mfma16(wO, (av_), eO);            \
                } } while (0)
            #define CONS_Q(s_, arr_, base_) do {                                       \
                u32x4 q_ = { (arr_)[(base_)], (arr_)[(base_)+1],                       \
                             (arr_)[(base_)+2], (arr_)[(base_)+3] };                   \
                bf16x8 av_ = __builtin_bit_cast(bf16x8, q_);                           \
                CONS(s_, av_); } while (0)

            if (layer) {
                const unsigned* hp = (const unsigned*)
                    (hx1b + par * BATCH * KDIM + b * KDIM + klo);
                unsigned ahA[64], ahB[32], ahC[32];
                #pragma unroll
                for (int s = 0; s < 16; ++s)
                    #pragma unroll
                    for (int d = 0; d < 4; ++d)
                        ahA[s * 4 + d] = ld_coh32(hp + s * 16 + d);
                #pragma unroll
                for (int s = 16; s < 24; ++s)
                    #pragma unroll
                    for (int d = 0; d < 4; ++d)
                        ahB[(s - 16) * 4 + d] = ld_coh32(hp + s * 16 + d);
                #pragma unroll
                for (int s = 0; s < 16; ++s) CONS_Q(s, ahA, s * 4);
                #pragma unroll
                for (int s = 24; s < 32; ++s)
                    #pragma unroll
                    for (int d = 0; d < 4; ++d)
                        ahC[(s - 24) * 4 + d] = ld_coh32(hp + s * 16 + d);
                #pragma unroll
                for (int s = 16; s < 24; ++s) CONS_Q(s, ahB, (s - 16) * 4);
                #pragma unroll
                for (int s = 24; s < 32; ++s) CONS_Q(s, ahC, (s - 24) * 4);
            } else {
                const unsigned* hp = (const unsigned*)
                    (h0b + par * BATCH * DH + b * DH + klo);
                unsigned ahA[64];
                #pragma unroll
                for (int s = 0; s < 16; ++s)
                    #pragma unroll
                    for (int d = 0; d < 4; ++d)
                        ahA[s * 4 + d] = ld_coh32(hp + s * 16 + d);
                // consume x-part from seq (normal cached loads) while h flies
                const float* sp = seq + ((size_t)t * BATCH + b) * DH + klo;
                #pragma unroll
                for (int s = 16; s < 32; ++s) {
                    float4 v0 = *(const float4*)(sp + (s - 16) * 32);
                    float4 v1 = *(const float4*)(sp + (s - 16) * 32 + 4);
                    u16x8 tv;
                    tv[0]=f2bf(v0.x); tv[1]=f2bf(v0.y); tv[2]=f2bf(v0.z); tv[3]=f2bf(v0.w);
                    tv[4]=f2bf(v1.x); tv[5]=f2bf(v1.y); tv[6]=f2bf(v1.z); tv[7]=f2bf(v1.w);
                    bf16x8 av = __builtin_bit_cast(bf16x8, tv);
                    CONS(s, av);
                }
                #pragma unroll
                for (int s = 0; s < 16; ++s) CONS_Q(s, ahA, s * 4);
            }
            #undef CONS_Q
            #undef CONS

            float hv[4];
            #pragma unroll
            for (int r = 0; r < 4; ++r) {
                float fg = sigmoid_f(eF[r] + oF[r] + bFa[r]);
                float ig = sigmoid_f(eI[r] + oI[r] + bIa[r]);
                float ct = tanh_f  (eC[r] + oC[r] + bCa[r]);
                float og = sigmoid_f(eO[r] + oO[r] + bOa[r]);
                float cn = fg * cs[r] + ig * ct;
                cs[r] = cn;
                hv[r]  = og * tanh_f(cn);
            }
            const unsigned d0 = (unsigned)f2bf(hv[0]) | ((unsigned)f2bf(hv[1]) << 16);
            const unsigned d1 = (unsigned)f2bf(hv[2]) | ((unsigned)f2bf(hv[3]) << 16);
            const int npar = (it + 1) & 1;
            if (!layer) {
                unsigned* p0 = (unsigned*)(h0b + npar * BATCH * DH + b * DH + jq);
                st_coh32(p0, d0); st_coh32(p0 + 1, d1);
                unsigned* p1 = (unsigned*)(hx1b + npar * BATCH * KDIM + b * KDIM + DH + jq);
                st_coh32(p1, d0); st_coh32(p1 + 1, d1);
                if (t == S_LEN - 1) {
                    float* po = out + (size_t)S_LEN * BATCH * DH + (size_t)b * DH + jq;
                    #pragma unroll
                    for (int r = 0; r < 4; ++r) __builtin_nontemporal_store(hv[r], po + r);
                }
            } else {
                unsigned* p1 = (unsigned*)(hx1b + npar * BATCH * KDIM + b * KDIM + jq);
                st_coh32(p1, d0); st_coh32(p1 + 1, d1);
                float* po = out + ((size_t)t * BATCH + b) * DH + jq;
                #pragma unroll
                for (int r = 0; r < 4; ++r) __builtin_nontemporal_store(hv[r], po + r);
                if (t == S_LEN - 1) {
                    float* pl = out + (size_t)S_LEN * BATCH * DH + (size_t)BATCH * DH
                                    + (size_t)b * DH + jq;
                    #pragma unroll
                    for (int r = 0; r < 4; ++r) __builtin_nontemporal_store(hv[r], pl + r);
                }
            }
        }

        // ---- fence-free flag barrier ----
        // __syncthreads drains each wave's vmcnt(0): every sc0sc1 h-store is
        // acked at the coherence point before tid0 publishes the flag.
        // Consumers only read h via sc0sc1 bypass loads -> no acquire needed;
        // seq/weights/biases stay L2-cached for the whole sequence.
        if (it < S_LEN) {
            __syncthreads();
            if (tid == 0)
                __hip_atomic_store(&flags[wg], (unsigned)(it + 1),
                                   __ATOMIC_RELAXED, __HIP_MEMORY_SCOPE_AGENT);
            if (wave == 0) {
                unsigned v;
                do {
                    __builtin_amdgcn_s_sleep(1);
                    v = __hip_atomic_load(&flags[lane], __ATOMIC_RELAXED,
                                          __HIP_MEMORY_SCOPE_AGENT);
                } while (!__all((int)(v >= (unsigned)(it + 1))));
            }
            __syncthreads();
            __builtin_amdgcn_sched_barrier(0);
        }
    }
}

extern "C" void kernel_launch(void* const* d_in, const int* in_sizes, int n_in,
                              void* d_out, int out_size, void* d_ws, size_t ws_size,
                              hipStream_t stream) {
    const float* seq    = (const float*)d_in[0];
    const float* h_init = (const float*)d_in[1];
    const float* Wf     = (const float*)d_in[2];
    const float* Bf     = (const float*)d_in[3];
    const float* Wi     = (const float*)d_in[4];
    const float* Bi     = (const float*)d_in[5];
    const float* Wc     = (const float*)d_in[6];
    const float* Bc     = (const float*)d_in[7];
    const float* Wo     = (const float*)d_in[8];
    const float* Bo     = (const float*)d_in[9];
    float* out          = (float*)d_out;
    unsigned short* ws  = (unsigned short*)d_ws;

    hipFuncSetAttribute((const void*)lstm_main,
                        hipFuncAttributeMaxDynamicSharedMemorySize, LDS_BYTES);

    hipLaunchKernelGGL(lstm_init, dim3(128), dim3(THREADS), 0, stream, seq, h_init, ws);

    void* args[] = { (void*)&seq,
                     (void*)&Wf, (void*)&Bf,
                     (void*)&Wi, (void*)&Bi,
                     (void*)&Wc, (void*)&Bc,
                     (void*)&Wo, (void*)&Bo,
                     (void*)&out, (void*)&ws };
    hipLaunchCooperativeKernel((void*)lstm_main, dim3(NWG), dim3(THREADS),
                               args, LDS_BYTES, stream);
}

// Round 8
// 8709.663 us; speedup vs baseline: 1.0708x; 1.0708x over previous
//
#include <hip/hip_runtime.h>
#include <hip/hip_bf16.h>

#define S_LEN   512
#define BATCH   64
#define DH      512
#define KDIM    1024      // 2*DH (concat [h, x])
#define NCOLS   64        // 4 gates * 16 hidden units per WG
#define WGL     32        // WGs per layer
#define NWG     64
#define THREADS 256
#define LDS_BYTES (NCOLS * KDIM * 2)   // 131072 B weights per WG
#define FLAG_STRIDE 32                 // uints: one flag per 128-B line

typedef __attribute__((ext_vector_type(8))) unsigned short u16x8;
typedef __attribute__((ext_vector_type(8))) __bf16         bf16x8;
typedef __attribute__((ext_vector_type(4))) float          f32x4;
typedef __attribute__((ext_vector_type(4))) unsigned       u32x4;

__device__ __forceinline__ unsigned short f2bf(float f) {
    unsigned u = __float_as_uint(f);
    return (unsigned short)((u + 0x7fffu + ((u >> 16) & 1u)) >> 16);   // RNE
}
__device__ __forceinline__ float sigmoid_f(float x) { return 1.f / (1.f + __expf(-x)); }
__device__ __forceinline__ float tanh_f(float x) {
    float e = __expf(2.f * x);
    return 1.f - 2.f / (e + 1.f);
}
__device__ __forceinline__ f32x4 mfma16(bf16x8 a, bf16x8 b, f32x4 c) {
    return __builtin_amdgcn_mfma_f32_16x16x32_bf16(a, b, c, 0, 0, 0);
}
// 32-bit agent-scope relaxed atomics (proven instruction class, compiler-tracked).
__device__ __forceinline__ unsigned ld_coh32(const unsigned* p) {
    return __hip_atomic_load(p, __ATOMIC_RELAXED, __HIP_MEMORY_SCOPE_AGENT);
}
__device__ __forceinline__ void st_coh32(unsigned* p, unsigned v) {
    __hip_atomic_store(p, v, __ATOMIC_RELAXED, __HIP_MEMORY_SCOPE_AGENT);
}

// ws layout:
//   ushort[0]      : h0buf [2][64][512]  bf16    layer0 h ping-pong
//   ushort[65536]  : hx1buf[2][64][1024] bf16    layer1 [h,x] ping-pong
//   byte 393216    : flags[64 * 32] uint         per-WG flag, one per 128-B line
#define WS_H0    0
#define WS_HX1   (2 * BATCH * DH)
#define WS_BAR_B 393216

__global__ void lstm_init(const float* __restrict__ seq,
                          const float* __restrict__ h_init,
                          unsigned short* __restrict__ ws) {
    int i = blockIdx.x * blockDim.x + threadIdx.x;   // 0 .. 32767
    unsigned* flags = (unsigned*)((char*)ws + WS_BAR_B);
    if (i < NWG) flags[i * FLAG_STRIDE] = 0;         // re-zeroed every launch
    if (i < BATCH * DH) {
        int row = i >> 9;
        int col = i & 511;
        ws[WS_H0 + row * DH + col] = f2bf(h_init[i]);                    // h0 par0
        ws[WS_HX1 + BATCH * KDIM + row * KDIM + col] =                   // hx1 par1 h-part
            f2bf(h_init[(size_t)BATCH * DH + i]);
    }
}

__global__ __launch_bounds__(THREADS, 1)
void lstm_main(const float* __restrict__ seq,
               const float* __restrict__ Wf, const float* __restrict__ Bf,
               const float* __restrict__ Wi, const float* __restrict__ Bi,
               const float* __restrict__ Wc, const float* __restrict__ Bc,
               const float* __restrict__ Wo, const float* __restrict__ Bo,
               float* __restrict__ out, unsigned short* __restrict__ ws)
{
    extern __shared__ unsigned short wlds[];   // [NCOLS][KDIM] bf16, XOR-swizzled

    const int wg    = blockIdx.x;
    const int layer = (wg >= WGL) ? 1 : 0;
    const int wid   = layer ? wg - WGL : wg;
    const int jbase = wid * 16;
    const int tid   = threadIdx.x;
    const int lane  = tid & 63;
    const int wave  = tid >> 6;

    unsigned short* h0b  = ws + WS_H0;
    unsigned short* hx1b = ws + WS_HX1;
    unsigned* flags = (unsigned*)((char*)ws + WS_BAR_B);

    // ---- stage this WG's weight slice into LDS (bf16, swizzled), once ----
    {
        const size_t woff = (size_t)layer * KDIM * DH;
        const float* Wg[4] = { Wf + woff, Wi + woff, Wc + woff, Wo + woff };
        for (int idx = tid; idx < NCOLS * KDIM; idx += THREADS) {
            int mcol = idx & (NCOLS - 1);          // gate*16 + unit
            int k    = idx >> 6;
            float w  = Wg[mcol >> 4][(size_t)k * DH + jbase + (mcol & 15)];
            unsigned byte = ((unsigned)mcol * 2048u + (unsigned)k * 2u)
                          ^ (((unsigned)mcol & 7u) << 4);
            wlds[byte >> 1] = f2bf(w);
        }
    }

    // ---- transposed-MFMA geometry: A=weights (rows=16 units), B=acts (cols=16 batch)
    // D mapping (m89): col = lane&15 -> batch, row = (lane>>4)*4 + r -> unit.
    const int ln  = lane & 15;
    const int lq  = lane >> 4;
    const int b   = wave * 16 + ln;          // this lane's batch row
    const int jq  = jbase + (lq << 2);       // first of 4 consecutive unit cols
    const int klo = lq * 8;                  // k offset within each K=32 chunk
    const unsigned sw  = ((unsigned)(lane & 7)) << 4;
    const unsigned wbF = (0u * 16 + (unsigned)ln) * 2048u;
    const unsigned wbI = (1u * 16 + (unsigned)ln) * 2048u;
    const unsigned wbC = (2u * 16 + (unsigned)ln) * 2048u;
    const unsigned wbO = (3u * 16 + (unsigned)ln) * 2048u;

    float bFa[4], bIa[4], bCa[4], bOa[4];
    #pragma unroll
    for (int r = 0; r < 4; ++r) {
        bFa[r] = Bf[layer * DH + jq + r];
        bIa[r] = Bi[layer * DH + jq + r];
        bCa[r] = Bc[layer * DH + jq + r];
        bOa[r] = Bo[layer * DH + jq + r];
    }
    __syncthreads();

    float cs[4] = {0.f, 0.f, 0.f, 0.f};

    for (int it = 0; it <= S_LEN; ++it) {
        const bool active = layer ? (it >= 1) : (it < S_LEN);
        const int  t      = layer ? it - 1 : it;

        if (active) {
            const int par = it & 1;
            f32x4 eF = {0,0,0,0}, eI = {0,0,0,0}, eC = {0,0,0,0}, eO = {0,0,0,0};
            f32x4 oF = {0,0,0,0}, oI = {0,0,0,0}, oC = {0,0,0,0}, oO = {0,0,0,0};

            #define CONS(s_, av_) do {                                                 \
                const unsigned kb = ((unsigned)(s_) * 64u + (unsigned)klo * 2u) ^ sw;  \
                bf16x8 wF = __builtin_bit_cast(bf16x8, *(const u16x8*)((const char*)wlds + wbF + kb)); \
                bf16x8 wI = __builtin_bit_cast(bf16x8, *(const u16x8*)((const char*)wlds + wbI + kb)); \
                bf16x8 wC = __builtin_bit_cast(bf16x8, *(const u16x8*)((const char*)wlds + wbC + kb)); \
                bf16x8 wO = __builtin_bit_cast(bf16x8, *(const u16x8*)((const char*)wlds + wbO + kb)); \
                if ((s_) & 1) {                                                        \
                    oF = mfma16(wF, (av_), oF); oI = mfma16(wI, (av_), oI);            \
                    oC = mfma16(wC, (av_), oC); oO = mfma16(wO, (av_), oO);            \
                } else {                                                               \
                    eF = mfma16(wF, (av_), eF); eI = mfma16(wI, (av_), eI);            \
                    eC = mfma16(wC, (av_), eC); eO = mfma16(wO, (av_), eO);            \
                } } while (0)
            #define CONS_Q(s_, arr_, base_) do {                                       \
                u32x4 q_ = { (arr_)[(base_)], (arr_)[(base_)+1],                       \
                             (arr_)[(base_)+2], (arr_)[(base_)+3] };                   \
                bf16x8 av_ = __builtin_bit_cast(bf16x8, q_);                           \
                CONS(s_, av_); } while (0)

            if (layer) {
                const unsigned* hp = (const unsigned*)
                    (hx1b + par * BATCH * KDIM + b * KDIM + klo);
                unsigned ahA[64], ahB[32], ahC[32];
                #pragma unroll
                for (int s = 0; s < 16; ++s)
                    #pragma unroll
                    for (int d = 0; d < 4; ++d)
                        ahA[s * 4 + d] = ld_coh32(hp + s * 16 + d);
                #pragma unroll
                for (int s = 16; s < 24; ++s)
                    #pragma unroll
                    for (int d = 0; d < 4; ++d)
                        ahB[(s - 16) * 4 + d] = ld_coh32(hp + s * 16 + d);
                #pragma unroll
                for (int s = 0; s < 16; ++s) CONS_Q(s, ahA, s * 4);
                #pragma unroll
                for (int s = 24; s < 32; ++s)
                    #pragma unroll
                    for (int d = 0; d < 4; ++d)
                        ahC[(s - 24) * 4 + d] = ld_coh32(hp + s * 16 + d);
                #pragma unroll
                for (int s = 16; s < 24; ++s) CONS_Q(s, ahB, (s - 16) * 4);
                #pragma unroll
                for (int s = 24; s < 32; ++s) CONS_Q(s, ahC, (s - 24) * 4);
            } else {
                const unsigned* hp = (const unsigned*)
                    (h0b + par * BATCH * DH + b * DH + klo);
                unsigned ahA[64];
                #pragma unroll
                for (int s = 0; s < 16; ++s)
                    #pragma unroll
                    for (int d = 0; d < 4; ++d)
                        ahA[s * 4 + d] = ld_coh32(hp + s * 16 + d);
                // consume x-part from seq (normal cached loads) while h flies
                const float* sp = seq + ((size_t)t * BATCH + b) * DH + klo;
                #pragma unroll
                for (int s = 16; s < 32; ++s) {
                    float4 v0 = *(const float4*)(sp + (s - 16) * 32);
                    float4 v1 = *(const float4*)(sp + (s - 16) * 32 + 4);
                    u16x8 tv;
                    tv[0]=f2bf(v0.x); tv[1]=f2bf(v0.y); tv[2]=f2bf(v0.z); tv[3]=f2bf(v0.w);
                    tv[4]=f2bf(v1.x); tv[5]=f2bf(v1.y); tv[6]=f2bf(v1.z); tv[7]=f2bf(v1.w);
                    bf16x8 av = __builtin_bit_cast(bf16x8, tv);
                    CONS(s, av);
                }
                #pragma unroll
                for (int s = 0; s < 16; ++s) CONS_Q(s, ahA, s * 4);
            }
            #undef CONS_Q
            #undef CONS

            float hv[4];
            #pragma unroll
            for (int r = 0; r < 4; ++r) {
                float fg = sigmoid_f(eF[r] + oF[r] + bFa[r]);
                float ig = sigmoid_f(eI[r] + oI[r] + bIa[r]);
                float ct = tanh_f  (eC[r] + oC[r] + bCa[r]);
                float og = sigmoid_f(eO[r] + oO[r] + bOa[r]);
                float cn = fg * cs[r] + ig * ct;
                cs[r] = cn;
                hv[r]  = og * tanh_f(cn);
            }
            const unsigned d0 = (unsigned)f2bf(hv[0]) | ((unsigned)f2bf(hv[1]) << 16);
            const unsigned d1 = (unsigned)f2bf(hv[2]) | ((unsigned)f2bf(hv[3]) << 16);
            const int npar = (it + 1) & 1;
            if (!layer) {
                unsigned* p0 = (unsigned*)(h0b + npar * BATCH * DH + b * DH + jq);
                st_coh32(p0, d0); st_coh32(p0 + 1, d1);
                unsigned* p1 = (unsigned*)(hx1b + npar * BATCH * KDIM + b * KDIM + DH + jq);
                st_coh32(p1, d0); st_coh32(p1 + 1, d1);
                if (t == S_LEN - 1) {
                    float* po = out + (size_t)S_LEN * BATCH * DH + (size_t)b * DH + jq;
                    #pragma unroll
                    for (int r = 0; r < 4; ++r) __builtin_nontemporal_store(hv[r], po + r);
                }
            } else {
                unsigned* p1 = (unsigned*)(hx1b + npar * BATCH * KDIM + b * KDIM + jq);
                st_coh32(p1, d0); st_coh32(p1 + 1, d1);
                float* po = out + ((size_t)t * BATCH + b) * DH + jq;
                #pragma unroll
                for (int r = 0; r < 4; ++r) __builtin_nontemporal_store(hv[r], po + r);
                if (t == S_LEN - 1) {
                    float* pl = out + (size_t)S_LEN * BATCH * DH + (size_t)BATCH * DH
                                    + (size_t)b * DH + jq;
                    #pragma unroll
                    for (int r = 0; r < 4; ++r) __builtin_nontemporal_store(hv[r], pl + r);
                }
            }
        }

        // ---- fence-free flag barrier, one flag per 128-B line ----
        // __syncthreads drains each wave's vmcnt(0): every sc0sc1 h-store is
        // acked at the coherence point before tid0 publishes the flag.
        // Padding kills device-scope false sharing: 64 writers on 64 lines,
        // pollers read 64 distinct lines in parallel (was: ~8000 same-line
        // transactions per step on 2 lines -> ~16 us/step serialization).
        if (it < S_LEN) {
            __syncthreads();
            if (tid == 0)
                __hip_atomic_store(&flags[wg * FLAG_STRIDE], (unsigned)(it + 1),
                                   __ATOMIC_RELAXED, __HIP_MEMORY_SCOPE_AGENT);
            if (wave == 0) {
                unsigned v;
                do {
                    __builtin_amdgcn_s_sleep(1);
                    v = __hip_atomic_load(&flags[lane * FLAG_STRIDE], __ATOMIC_RELAXED,
                                          __HIP_MEMORY_SCOPE_AGENT);
                } while (!__all((int)(v >= (unsigned)(it + 1))));
            }
            __syncthreads();
            __builtin_amdgcn_sched_barrier(0);
        }
    }
}

extern "C" void kernel_launch(void* const* d_in, const int* in_sizes, int n_in,
                              void* d_out, int out_size, void* d_ws, size_t ws_size,
                              hipStream_t stream) {
    const float* seq    = (const float*)d_in[0];
    const float* h_init = (const float*)d_in[1];
    const float* Wf     = (const float*)d_in[2];
    const float* Bf     = (const float*)d_in[3];
    const float* Wi     = (const float*)d_in[4];
    const float* Bi     = (const float*)d_in[5];
    const float* Wc     = (const float*)d_in[6];
    const float* Bc     = (const float*)d_in[7];
    const float* Wo     = (const float*)d_in[8];
    const float* Bo     = (const float*)d_in[9];
    float* out          = (float*)d_out;
    unsigned short* ws  = (unsigned short*)d_ws;

    hipFuncSetAttribute((const void*)lstm_main,
                        hipFuncAttributeMaxDynamicSharedMemorySize, LDS_BYTES);

    hipLaunchKernelGGL(lstm_init, dim3(128), dim3(THREADS), 0, stream, seq, h_init, ws);

    void* args[] = { (void*)&seq,
                     (void*)&Wf, (void*)&Bf,
                     (void*)&Wi, (void*)&Bi,
                     (void*)&Wc, (void*)&Bc,
                     (void*)&Wo, (void*)&Bo,
                     (void*)&out, (void*)&ws };
    hipLaunchCooperativeKernel((void*)lstm_main, dim3(NWG), dim3(THREADS),
                               args, LDS_BYTES, stream);
}